// Round 7
// baseline (181.678 us; speedup 1.0000x reference)
//
#include <hip/hip_runtime.h>
#include <math.h>

// CellSegmentationLoss: fused focal + dice + boundary-BCE + IoU-aux loss.
// Inputs: d_in[0]=pred_masks (16*1*1024*1024 f32), d_in[1]=gt_masks (same),
//         d_in[2]=pred_iou (16 f32). Output: 1 f32 scalar.
//
// R10: DISCRIMINATING EXPERIMENT -- per-wave load-window depth.
// Ledger:
//   R3 (46us, occ 30%) / R4 (56us, occ 58%) / R8 (50us, occ 29%) /
//   R9 (52us, occ 54%): every non-spilling structure delivers 2.7-2.9 TB/s,
//   INVARIANT to occupancy, block size, burst shape. FETCH pinned ~65MB.
//   R5/R6/R7: any >16-f4 live set spills catastrophically. Stay < 64 VGPR.
//   (R8's "L3-warm same speed" was a counter artifact: FETCH=NaN rows.)
// Two live hypotheses:
//   A) per-CU outstanding-request capacity saturated (~4KB/CU @ ~900cy)
//      -> nothing wave-side helps -> R10 changes NOTHING -> ROOFLINE.
//   B) per-wave window too shallow (4 loads) -> doubling to 8 loads/wave
//      (8KB in flight, sched_barrier-pinned, still ~52 VGPR) -> 38-44us.
// R10 doubles ONLY the window: rolled loop, 8 dwordx4 per body, counted
// vmcnt consume, bounds(256,8), 2048 blocks (one generation).

#define HW_PIX (1024 * 1024)
#define BATCH 16
constexpr int THREADS = 256;
constexpr int BLOCKS = 2048;                            // 8 / CU, 1 generation
constexpr int BLOCKS_PER_IMG = BLOCKS / BATCH;          // 128
constexpr int PIX_PER_BLOCK = HW_PIX / BLOCKS_PER_IMG;  // 8192
constexpr int F4_PER_THREAD = PIX_PER_BLOCK / (THREADS * 4);  // 8
constexpr int BODY_F4 = 4;                              // 4 f4/array per body
constexpr int LOOP_ITERS = F4_PER_THREAD / BODY_F4;     // 2

struct Accum {
  float fsum, csum, isum, psum;
  float tcnt, bicnt, bpcnt;   // counts as floats: exact for <=2^24
};

__device__ __forceinline__ void process4(const float4 xv, const float4 tv,
                                         Accum& a) {
  const float* xs = reinterpret_cast<const float*>(&xv);
  const float* ts = reinterpret_cast<const float*>(&tv);
#pragma unroll
  for (int j = 0; j < 4; ++j) {
    const float xx = xs[j];
    const float tt = ts[j];
    const float e = __expf(-fabsf(xx));                // exp(-|x|) in (0,1]
    const float s = 1.0f + e;
    const float r = __builtin_amdgcn_rcpf(s);
    const float p = (xx >= 0.0f) ? r : e * r;          // sigmoid(x)
    const float ce = fmaxf(xx, 0.0f) - xx * tt + __logf(s);
    const float om = fmaf(tt, 1.0f - 2.0f * p, p);     // 1 - p_t
    const float at = 0.75f - 0.5f * tt;                // alpha_t
    a.fsum += at * ce * om * om;
    a.csum += ce;
    a.isum = fmaf(p, tt, a.isum);
    a.psum += p;
    const float pb = (xx > 0.0f) ? 1.0f : 0.0f;        // p>0.5 <=> x>0
    a.tcnt += tt;                                      // tt in {0,1}
    a.bpcnt += pb;
    a.bicnt += pb * tt;
  }
}

__global__ __launch_bounds__(THREADS, 8) void
loss_partial(const float* __restrict__ x, const float* __restrict__ t,
             float* __restrict__ acc) {
  const int b = blockIdx.x / BLOCKS_PER_IMG;
  const long base = (long)blockIdx.x * PIX_PER_BLOCK;
  const float4* __restrict__ x4 = (const float4*)(x + base);
  const float4* __restrict__ t4 = (const float4*)(t + base);
  const int tid = threadIdx.x;

  Accum a = {0.f, 0.f, 0.f, 0.f, 0.f, 0.f, 0.f};

  // Rolled loop, 8 dwordx4 per body (8KB/wave in flight). The load group is
  // pinned above the compute (R3-proven pattern); the compiler then consumes
  // with counted vmcnt while the remaining loads fly. 32 data VGPRs + ~20
  // overhead ~= 52 < the 64-VGPR cap -> no spill expected (verify WRITE_SIZE).
#pragma unroll 1
  for (int i = 0; i < LOOP_ITERS; ++i) {
    const int o = tid + i * BODY_F4 * THREADS;
    const float4 x0 = x4[o + 0 * THREADS];
    const float4 t0 = t4[o + 0 * THREADS];
    const float4 x1 = x4[o + 1 * THREADS];
    const float4 t1 = t4[o + 1 * THREADS];
    const float4 x2 = x4[o + 2 * THREADS];
    const float4 t2 = t4[o + 2 * THREADS];
    const float4 x3 = x4[o + 3 * THREADS];
    const float4 t3 = t4[o + 3 * THREADS];
    __builtin_amdgcn_sched_barrier(0);
    process4(x0, t0, a);
    process4(x1, t1, a);
    process4(x2, t2, a);
    process4(x3, t3, a);
  }

  __shared__ float red[THREADS / 64][7];
  const int lane = threadIdx.x & 63;
  const int wave = threadIdx.x >> 6;
  const float vals[7] = {a.fsum, a.csum, a.isum, a.psum,
                         a.tcnt, a.bicnt, a.bpcnt};
#pragma unroll
  for (int k = 0; k < 7; ++k) {
    float v = vals[k];
#pragma unroll
    for (int off = 32; off > 0; off >>= 1) v += __shfl_down(v, off);
    if (lane == 0) red[wave][k] = v;
  }
  __syncthreads();
  if (threadIdx.x < 7) {
    const float s = red[0][threadIdx.x] + red[1][threadIdx.x] +
                    red[2][threadIdx.x] + red[3][threadIdx.x];
    atomicAdd(&acc[b * 16 + threadIdx.x], s);  // stride 16: own line/image
  }
}

__global__ void loss_final(const float* __restrict__ acc,
                           const float* __restrict__ pred_iou,
                           float* __restrict__ out) {
  constexpr float SMOOTH = 1e-6f;
  const int lane = threadIdx.x;  // one wave (64), lanes 0..15 active
  float F = 0.f, C = 0.f, D = 0.f, Q = 0.f;
  if (lane < BATCH) {
    const float* a = acc + lane * 16;
    F = a[0];
    C = a[1];
    const float I = a[2], P = a[3], T = a[4], BI = a[5], BP = a[6];
    D = (2.0f * I + SMOOTH) / (P + T + SMOOTH);            // dice term
    const float iou = (BI + SMOOTH) / (BP + T - BI + SMOOTH);
    const float d = pred_iou[lane] - iou;
    Q = d * d;
  }
#pragma unroll
  for (int off = 32; off > 0; off >>= 1) {
    F += __shfl_down(F, off);
    C += __shfl_down(C, off);
    D += __shfl_down(D, off);
    Q += __shfl_down(Q, off);
  }
  if (lane == 0) {
    const float invN = 1.0f / (float)((long)BATCH * HW_PIX);
    const float focal = F * invN;
    const float dice = 1.0f - D * (1.0f / (float)BATCH);
    const float half_boundary = C * invN;  // 0.5 * (2.0 * mean(ce))
    const float iou_loss = Q * (1.0f / (float)BATCH);
    out[0] = focal + dice + half_boundary + 0.1f * iou_loss;
  }
}

extern "C" void kernel_launch(void* const* d_in, const int* in_sizes, int n_in,
                              void* d_out, int out_size, void* d_ws,
                              size_t ws_size, hipStream_t stream) {
  const float* x = (const float*)d_in[0];
  const float* t = (const float*)d_in[1];
  const float* piou = (const float*)d_in[2];
  float* acc = (float*)d_ws;  // BATCH*16 floats

  hipMemsetAsync(acc, 0, BATCH * 16 * sizeof(float), stream);
  loss_partial<<<BLOCKS, THREADS, 0, stream>>>(x, t, acc);
  loss_final<<<1, 64, 0, stream>>>(acc, piou, (float*)d_out);
}

// Round 8
// 154.041 us; speedup vs baseline: 1.1794x; 1.1794x over previous
//
#include <hip/hip_runtime.h>
#include <math.h>

// CellSegmentationLoss: fused focal + dice + boundary-BCE + IoU-aux loss.
// Inputs: d_in[0]=pred_masks (16*1*1024*1024 f32), d_in[1]=gt_masks (same),
//         d_in[2]=pred_iou (16 f32). Output: 1 f32 scalar.
//
// R11: A/B vs R9 -- ONLY the macro sweep order changes.
// Ledger:
//   R3 46us / R4 56 / R8 50 / R9 52: all non-spilling structures deliver
//     2.7-3.0 TB/s TOTAL traffic, invariant to occupancy (29-70%), block
//     size, burst shape. R10 (spilled): useful+scratch ALSO = 2.97 TB/s.
//   R5/R6/R7/R10: any compiler-visible live set >~8 f4 spills. Rolled
//     2+2-f4 body (R8/R9, VGPR 32-36) is the only safe steady-state shape.
//   Reframe: the "6.3 TB/s" copy ubench counts read+write => ~3.15 TB/s
//     per direction. Read-only floor at that rate = 43us; R3 = 46us (93%).
// Last untested axis: sweep order. Ours = 2048 private 4KB fronts/stream;
// copy ubench = one dense grid-stride front (long DRAM-page runs/channel).
// R11: the 128 blocks of an image interleave at 4KB granularity => each
// image is swept by ONE contiguous 512KB front advancing 4x. Register
// regime, body, grid, bounds identical to R9.
// If unchanged (49-53us): read-path ceiling confirmed -> revert + ROOFLINE.

#define HW_PIX (1024 * 1024)
#define BATCH 16
constexpr int THREADS = 256;
constexpr int BLOCKS = 2048;                            // 8 / CU, 1 generation
constexpr int BLOCKS_PER_IMG = BLOCKS / BATCH;          // 128
constexpr int F4_PER_IMG = HW_PIX / 4;                  // 262144
constexpr int THREADS_PER_IMG = BLOCKS_PER_IMG * THREADS;     // 32768
constexpr int F4_PER_THREAD = F4_PER_IMG / THREADS_PER_IMG;   // 8
constexpr int LOOP_ITERS = F4_PER_THREAD / 2;           // 4 (2 f4/array/iter)

struct Accum {
  float fsum, csum, isum, psum;
  float tcnt, bicnt, bpcnt;   // counts as floats: exact for <=2^24
};

__device__ __forceinline__ void process4(const float4 xv, const float4 tv,
                                         Accum& a) {
  const float* xs = reinterpret_cast<const float*>(&xv);
  const float* ts = reinterpret_cast<const float*>(&tv);
#pragma unroll
  for (int j = 0; j < 4; ++j) {
    const float xx = xs[j];
    const float tt = ts[j];
    const float e = __expf(-fabsf(xx));                // exp(-|x|) in (0,1]
    const float s = 1.0f + e;
    const float r = __builtin_amdgcn_rcpf(s);
    const float p = (xx >= 0.0f) ? r : e * r;          // sigmoid(x)
    const float ce = fmaxf(xx, 0.0f) - xx * tt + __logf(s);
    const float om = fmaf(tt, 1.0f - 2.0f * p, p);     // 1 - p_t
    const float at = 0.75f - 0.5f * tt;                // alpha_t
    a.fsum += at * ce * om * om;
    a.csum += ce;
    a.isum = fmaf(p, tt, a.isum);
    a.psum += p;
    const float pb = (xx > 0.0f) ? 1.0f : 0.0f;        // p>0.5 <=> x>0
    a.tcnt += tt;                                      // tt in {0,1}
    a.bpcnt += pb;
    a.bicnt += pb * tt;
  }
}

__global__ __launch_bounds__(THREADS, 8) void
loss_partial(const float* __restrict__ x, const float* __restrict__ t,
             float* __restrict__ acc) {
  const int b = blockIdx.x >> 7;                 // image = blockIdx / 128
  const int grp = blockIdx.x & 127;              // position within image group
  const float4* __restrict__ x4 = (const float4*)x + (long)b * F4_PER_IMG;
  const float4* __restrict__ t4 = (const float4*)t + (long)b * F4_PER_IMG;
  const int tid = threadIdx.x;
  // Cooperative wide-front sweep: the image's 128 blocks interleave at 4KB
  // granularity; successive iterations advance the whole 512KB front.
  const int pos = grp * THREADS + tid;           // 0..32767, f4 units

  Accum a = {0.f, 0.f, 0.f, 0.f, 0.f, 0.f, 0.f};

  // Rolled 2+2 body -- the R8/R9 proven non-spilling shape. Do NOT
  // full-unroll, hand-prefetch, or sched_barrier (R5/R6/R7/R10 spills).
#pragma unroll 1
  for (int i = 0; i < LOOP_ITERS; ++i) {
    const int o = pos + (2 * i) * THREADS_PER_IMG;
    const float4 x0 = x4[o];
    const float4 t0 = t4[o];
    const float4 x1 = x4[o + THREADS_PER_IMG];
    const float4 t1 = t4[o + THREADS_PER_IMG];
    process4(x0, t0, a);
    process4(x1, t1, a);
  }

  __shared__ float red[THREADS / 64][7];
  const int lane = threadIdx.x & 63;
  const int wave = threadIdx.x >> 6;
  const float vals[7] = {a.fsum, a.csum, a.isum, a.psum,
                         a.tcnt, a.bicnt, a.bpcnt};
#pragma unroll
  for (int k = 0; k < 7; ++k) {
    float v = vals[k];
#pragma unroll
    for (int off = 32; off > 0; off >>= 1) v += __shfl_down(v, off);
    if (lane == 0) red[wave][k] = v;
  }
  __syncthreads();
  if (threadIdx.x < 7) {
    const float s = red[0][threadIdx.x] + red[1][threadIdx.x] +
                    red[2][threadIdx.x] + red[3][threadIdx.x];
    atomicAdd(&acc[b * 16 + threadIdx.x], s);  // stride 16: own line/image
  }
}

__global__ void loss_final(const float* __restrict__ acc,
                           const float* __restrict__ pred_iou,
                           float* __restrict__ out) {
  constexpr float SMOOTH = 1e-6f;
  const int lane = threadIdx.x;  // one wave (64), lanes 0..15 active
  float F = 0.f, C = 0.f, D = 0.f, Q = 0.f;
  if (lane < BATCH) {
    const float* a = acc + lane * 16;
    F = a[0];
    C = a[1];
    const float I = a[2], P = a[3], T = a[4], BI = a[5], BP = a[6];
    D = (2.0f * I + SMOOTH) / (P + T + SMOOTH);            // dice term
    const float iou = (BI + SMOOTH) / (BP + T - BI + SMOOTH);
    const float d = pred_iou[lane] - iou;
    Q = d * d;
  }
#pragma unroll
  for (int off = 32; off > 0; off >>= 1) {
    F += __shfl_down(F, off);
    C += __shfl_down(C, off);
    D += __shfl_down(D, off);
    Q += __shfl_down(Q, off);
  }
  if (lane == 0) {
    const float invN = 1.0f / (float)((long)BATCH * HW_PIX);
    const float focal = F * invN;
    const float dice = 1.0f - D * (1.0f / (float)BATCH);
    const float half_boundary = C * invN;  // 0.5 * (2.0 * mean(ce))
    const float iou_loss = Q * (1.0f / (float)BATCH);
    out[0] = focal + dice + half_boundary + 0.1f * iou_loss;
  }
}

extern "C" void kernel_launch(void* const* d_in, const int* in_sizes, int n_in,
                              void* d_out, int out_size, void* d_ws,
                              size_t ws_size, hipStream_t stream) {
  const float* x = (const float*)d_in[0];
  const float* t = (const float*)d_in[1];
  const float* piou = (const float*)d_in[2];
  float* acc = (float*)d_ws;  // BATCH*16 floats

  hipMemsetAsync(acc, 0, BATCH * 16 * sizeof(float), stream);
  loss_partial<<<BLOCKS, THREADS, 0, stream>>>(x, t, acc);
  loss_final<<<1, 64, 0, stream>>>(acc, piou, (float*)d_out);
}